// Round 2
// baseline (77681.409 us; speedup 1.0000x reference)
//
#include <hip/hip_runtime.h>
#include <math.h>

// ---------------------------------------------------------------------------
// PPNet (ViT-B/16 with token pruning + proto head), f32 correctness-first.
// B=64, D=768, H=12, DH=64, L=12, NP=196, tokens 197 -> 145 -> 122.
// ---------------------------------------------------------------------------

#define NB 64
#define ND 768
#define NH 12
#define NDH 64
#define NL 12
#define NPATCH 196

__device__ __forceinline__ float gelu_tanh(float x) {
    float x3 = x * x * x;
    return 0.5f * x * (1.0f + tanhf(0.7978845608028654f * (x + 0.044715f * x3)));
}

// ---------------- generic tiled f32 GEMM:  C (+)= act(A[M,K] @ W[K,N] + bias)
// ACT: 0 none, 1 gelu, 2 sigmoid.  ACC: accumulate into existing C.
// Requires M%64==0, N%64==0, K%16==0.
template <int ACT, bool ACC>
__global__ __launch_bounds__(256) void gemm_f32(
    const float* __restrict__ A, const float* __restrict__ W,
    const float* __restrict__ bias, float* __restrict__ C,
    int M, int N, int K)
{
    __shared__ float As[16][68];
    __shared__ float Bs[16][68];
    const int tid = threadIdx.y * 16 + threadIdx.x;
    const int m0 = blockIdx.y * 64;
    const int n0 = blockIdx.x * 64;
    const int tr = threadIdx.y * 4;
    const int tc = threadIdx.x * 4;

    const int la_m = tid >> 2;          // 0..63
    const int la_k = (tid & 3) * 4;     // 0,4,8,12
    const int lb_k = tid >> 4;          // 0..15
    const int lb_n = (tid & 15) * 4;    // 0..60

    float c[4][4] = {};

    for (int k0 = 0; k0 < K; k0 += 16) {
        float4 av = *reinterpret_cast<const float4*>(&A[(size_t)(m0 + la_m) * K + k0 + la_k]);
        As[la_k + 0][la_m] = av.x;
        As[la_k + 1][la_m] = av.y;
        As[la_k + 2][la_m] = av.z;
        As[la_k + 3][la_m] = av.w;
        float4 bv = *reinterpret_cast<const float4*>(&W[(size_t)(k0 + lb_k) * N + n0 + lb_n]);
        *reinterpret_cast<float4*>(&Bs[lb_k][lb_n]) = bv;
        __syncthreads();
#pragma unroll
        for (int kk = 0; kk < 16; ++kk) {
            float a0 = As[kk][tr + 0], a1 = As[kk][tr + 1], a2 = As[kk][tr + 2], a3 = As[kk][tr + 3];
            float b0 = Bs[kk][tc + 0], b1 = Bs[kk][tc + 1], b2 = Bs[kk][tc + 2], b3 = Bs[kk][tc + 3];
            c[0][0] += a0 * b0; c[0][1] += a0 * b1; c[0][2] += a0 * b2; c[0][3] += a0 * b3;
            c[1][0] += a1 * b0; c[1][1] += a1 * b1; c[1][2] += a1 * b2; c[1][3] += a1 * b3;
            c[2][0] += a2 * b0; c[2][1] += a2 * b1; c[2][2] += a2 * b2; c[2][3] += a2 * b3;
            c[3][0] += a3 * b0; c[3][1] += a3 * b1; c[3][2] += a3 * b2; c[3][3] += a3 * b3;
        }
        __syncthreads();
    }

#pragma unroll
    for (int i = 0; i < 4; ++i) {
#pragma unroll
        for (int j = 0; j < 4; ++j) {
            float val = c[i][j] + bias[n0 + tc + j];
            if (ACT == 1) val = gelu_tanh(val);
            if (ACT == 2) val = 1.0f / (1.0f + expf(-val));
            size_t off = (size_t)(m0 + tr + i) * N + (n0 + tc + j);
            if (ACC) C[off] += val; else C[off] = val;
        }
    }
}

// ---------------- im2col for 16x16/stride-16 patch conv (output 12544 x 768)
__global__ __launch_bounds__(256) void im2col_kernel(const float* __restrict__ x,
                                                     float* __restrict__ out)
{
    size_t idx = (size_t)blockIdx.x * 256 + threadIdx.x;
    if (idx >= (size_t)12544 * 768) return;
    int col = (int)(idx % 768);
    int row = (int)(idx / 768);
    int b = row / NPATCH;
    int p = row % NPATCH;
    int c = col >> 8;            // /256
    int r = (col & 255) >> 4;
    int j = col & 15;
    int ph = p / 14, pw = p % 14;
    out[idx] = x[((size_t)(b * 3 + c) * 224 + (ph * 16 + r)) * 224 + (pw * 16 + j)];
}

// ---------------- transpose: dst[C x R], dst[c*R+r] = src[r*C+c]
__global__ __launch_bounds__(256) void transpose_k(const float* __restrict__ src,
                                                   float* __restrict__ dst, int R, int C)
{
    size_t idx = (size_t)blockIdx.x * 256 + threadIdx.x;
    if (idx >= (size_t)R * C) return;
    int r = (int)(idx / C);
    int c = (int)(idx % C);
    dst[(size_t)c * R + r] = src[idx];
}

// ---------------- build tok = [cls ; patches] + pos
__global__ __launch_bounds__(256) void build_tok(const float* __restrict__ pe,
                                                 const float* __restrict__ cls_tok,
                                                 const float* __restrict__ pos,
                                                 float* __restrict__ tok)
{
    int bid = blockIdx.x;
    int b = bid / 197, r = bid % 197;
    int t = threadIdx.x;
    float* dst = tok + (size_t)bid * ND;
#pragma unroll
    for (int s = 0; s < 3; ++s) {
        int d = t + s * 256;
        float v;
        if (r == 0) v = cls_tok[d];
        else        v = pe[(size_t)(b * NPATCH + r - 1) * ND + d];
        dst[d] = v + pos[(size_t)r * ND + d];
    }
}

__global__ __launch_bounds__(256) void init_cls(float* __restrict__ cls, float* __restrict__ acc)
{
    int b = blockIdx.x, t = threadIdx.x;
    if (t < NPATCH) { cls[b * NPATCH + t] = 1.0f; acc[b * NPATCH + t] = 0.0f; }
}

// ---------------- LayerNorm (row = 768), eps 1e-6, two-pass
__global__ __launch_bounds__(256) void ln_kernel(const float* __restrict__ x,
                                                 const float* __restrict__ g,
                                                 const float* __restrict__ b,
                                                 float* __restrict__ out)
{
    __shared__ float red[256];
    int row = blockIdx.x, t = threadIdx.x;
    const float* xr = x + (size_t)row * ND;
    float v0 = xr[t], v1 = xr[t + 256], v2 = xr[t + 512];
    red[t] = v0 + v1 + v2;
    __syncthreads();
    for (int w = 128; w >= 1; w >>= 1) { if (t < w) red[t] += red[t + w]; __syncthreads(); }
    float mean = red[0] * (1.0f / 768.0f);
    __syncthreads();
    float d0 = v0 - mean, d1 = v1 - mean, d2 = v2 - mean;
    red[t] = d0 * d0 + d1 * d1 + d2 * d2;
    __syncthreads();
    for (int w = 128; w >= 1; w >>= 1) { if (t < w) red[t] += red[t + w]; __syncthreads(); }
    float rstd = rsqrtf(red[0] * (1.0f / 768.0f) + 1e-6f);
    float* o = out + (size_t)row * ND;
    o[t]       = d0 * rstd * g[t]       + b[t];
    o[t + 256] = d1 * rstd * g[t + 256] + b[t + 256];
    o[t + 512] = d2 * rstd * g[t + 512] + b[t + 512];
}

// ---------------- attention: one block per (b,h), loops over queries.
// qkv: (B, N, 2304) with cols [q | k | v], each head-major h*64+dh.
// o: (B, N, 768).  cls_acc += prob(q=0, key t)/12 for t>=1.
__global__ __launch_bounds__(256) void attn_kernel(const float* __restrict__ qkv,
                                                   float* __restrict__ o,
                                                   float* __restrict__ cls_acc,
                                                   int N)
{
    __shared__ float qv[64];
    __shared__ float sc[256];
    __shared__ float red[256];
    int bh = blockIdx.x;
    int b = bh / NH, h = bh % NH;
    int t = threadIdx.x;
    const float* base = qkv + (size_t)b * N * 2304;

    for (int q = 0; q < N; ++q) {
        if (t < 64) qv[t] = base[(size_t)q * 2304 + h * 64 + t];
        __syncthreads();
        float s = -1e30f;
        if (t < N) {
            const float* kr = base + (size_t)t * 2304 + 768 + h * 64;
            float acc = 0.0f;
#pragma unroll
            for (int d = 0; d < 64; ++d) acc += qv[d] * kr[d];
            s = acc * 0.125f;
        }
        red[t] = s;
        __syncthreads();
        for (int w = 128; w >= 1; w >>= 1) { if (t < w) red[t] = fmaxf(red[t], red[t + w]); __syncthreads(); }
        float m = red[0];
        __syncthreads();
        float p = (t < N) ? expf(s - m) : 0.0f;
        red[t] = p;
        __syncthreads();
        for (int w = 128; w >= 1; w >>= 1) { if (t < w) red[t] += red[t + w]; __syncthreads(); }
        float inv = 1.0f / red[0];
        sc[t] = p;
        __syncthreads();
        if (q == 0 && t >= 1 && t < N)
            atomicAdd(&cls_acc[b * NPATCH + t - 1], p * inv * (1.0f / 12.0f));
        if (t < 64) {
            const float* vr = base + 1536 + h * 64 + t;
            float acc = 0.0f;
            for (int k = 0; k < N; ++k) acc += sc[k] * vr[(size_t)k * 2304];
            o[(size_t)(b * N + q) * ND + h * 64 + t] = acc * inv;
        }
        __syncthreads();
    }
}

// ---------------- cls_attn update: cls *= acc; cls /= sum; acc = 0
__global__ __launch_bounds__(256) void cls_update(float* __restrict__ cls,
                                                  float* __restrict__ acc, int n)
{
    __shared__ float red[256];
    int b = blockIdx.x, t = threadIdx.x;
    float v = 0.0f;
    if (t < n) v = cls[b * NPATCH + t] * acc[b * NPATCH + t];
    red[t] = v;
    __syncthreads();
    for (int w = 128; w >= 1; w >>= 1) { if (t < w) red[t] += red[t + w]; __syncthreads(); }
    float inv = 1.0f / red[0];
    if (t < n) { cls[b * NPATCH + t] = v * inv; acc[b * NPATCH + t] = 0.0f; }
}

// ---------------- top-k selection (stable, matches jax.lax.top_k + sort(idx))
__global__ __launch_bounds__(256) void prune_kernel(const float* __restrict__ cls,
                                                    int* __restrict__ idx, int n, int kk)
{
    __shared__ float v[256];
    __shared__ int keep[256];
    int b = blockIdx.x, t = threadIdx.x;
    v[t] = (t < n) ? cls[b * NPATCH + t] : -1e30f;
    __syncthreads();
    if (t < n) {
        float mv = v[t];
        int cnt = 0;
        for (int s = 0; s < n; ++s)
            cnt += (v[s] > mv) || (v[s] == mv && s < t);
        keep[t] = (cnt < kk) ? 1 : 0;
    }
    __syncthreads();
    if (t == 0) {
        int p = 0;
        for (int s = 0; s < n; ++s)
            if (keep[s]) idx[b * NPATCH + p++] = s;
    }
}

// ---------------- gather rows after prune (newN = kk+1 incl. cls token)
__global__ __launch_bounds__(256) void gather_kernel(const float* __restrict__ ti,
                                                     float* __restrict__ to,
                                                     const float* __restrict__ ci,
                                                     float* __restrict__ co,
                                                     const int* __restrict__ idx,
                                                     int newN, int oldN)
{
    int bid = blockIdx.x;
    int b = bid / newN, r = bid % newN;
    int t = threadIdx.x;
    int src = 0;
    if (r > 0) {
        int j = idx[b * NPATCH + r - 1];
        src = 1 + j;
        if (t == 0) co[b * NPATCH + r - 1] = ci[b * NPATCH + j];
    }
    const float* s = ti + (size_t)(b * oldN + src) * ND;
    float* d = to + (size_t)(b * newN + r) * ND;
    d[t] = s[t]; d[t + 256] = s[t + 256]; d[t + 512] = s[t + 512];
}

// ---------------- copy final img rows (tok rows 1..121) contiguous
__global__ __launch_bounds__(256) void copy_img(const float* __restrict__ tok,
                                                float* __restrict__ out)
{
    int bid = blockIdx.x;
    int b = bid / 121, r = bid % 121;
    int t = threadIdx.x;
    const float* s = tok + (size_t)(b * 122 + 1 + r) * ND;
    float* d = out + (size_t)bid * ND;
    d[t] = s[t]; d[t + 256] = s[t + 256]; d[t + 512] = s[t + 512];
}

// ---------------- proto distances + log-activation + max over positions
__global__ __launch_bounds__(128) void proto_kernel(const float* __restrict__ f,
                                                    const float* __restrict__ protos,
                                                    float* __restrict__ act)
{
    __shared__ float pw[128];
    __shared__ float red[128];
    int bid = blockIdx.x;
    int b = bid / 20, p = bid % 20;
    int t = threadIdx.x;
    pw[t] = protos[p * 128 + t];
    __syncthreads();
    float a = -1e30f;
    if (t < 121) {
        const float* fr = f + (size_t)(b * 121 + t) * 128;
        float x2 = 0.0f, xp = 0.0f, p2 = 0.0f;
#pragma unroll
        for (int c = 0; c < 128; ++c) {
            float fv = fr[c], pv = pw[c];
            x2 += fv * fv; xp += fv * pv; p2 += pv * pv;
        }
        float dist = fmaxf(x2 - 2.0f * xp + p2, 0.0f);
        a = logf((dist + 1.0f) / (dist + 1e-4f));
    }
    red[t] = a;
    __syncthreads();
    for (int w = 64; w >= 1; w >>= 1) { if (t < w) red[t] = fmaxf(red[t], red[t + w]); __syncthreads(); }
    if (t == 0) act[b * 20 + p] = red[0];
}

// ---------------- final tiny matmul: out[b,j] = sum_p act[b,p]*last_w[j,p]
__global__ __launch_bounds__(128) void final_kernel(const float* __restrict__ act,
                                                    const float* __restrict__ lw,
                                                    float* __restrict__ out)
{
    int i = threadIdx.x;
    if (i < 128) {
        int b = i >> 1, j = i & 1;
        float s = 0.0f;
#pragma unroll
        for (int p = 0; p < 20; ++p) s += act[b * 20 + p] * lw[j * 20 + p];
        out[i] = s;
    }
}

// ---------------------------------------------------------------------------
extern "C" void kernel_launch(void* const* d_in, const int* in_sizes, int n_in,
                              void* d_out, int out_size, void* d_ws, size_t ws_size,
                              hipStream_t stream)
{
    const float* x       = (const float*)d_in[0];
    const float* patch_w = (const float*)d_in[1];
    const float* patch_b = (const float*)d_in[2];
    const float* cls_tok = (const float*)d_in[3];
    const float* pos     = (const float*)d_in[4];
    const float* ln1_g   = (const float*)d_in[5];
    const float* ln1_b   = (const float*)d_in[6];
    const float* Wqkv    = (const float*)d_in[7];
    const float* bqkv    = (const float*)d_in[8];
    const float* Wo      = (const float*)d_in[9];
    const float* bo      = (const float*)d_in[10];
    const float* ln2_g   = (const float*)d_in[11];
    const float* ln2_b   = (const float*)d_in[12];
    const float* W1      = (const float*)d_in[13];
    const float* b1      = (const float*)d_in[14];
    const float* W2      = (const float*)d_in[15];
    const float* b2      = (const float*)d_in[16];
    const float* addon_w = (const float*)d_in[17];
    const float* addon_b = (const float*)d_in[18];
    const float* protos  = (const float*)d_in[19];
    const float* last_w  = (const float*)d_in[20];

    float* ws = (float*)d_ws;
    const size_t TOKN = (size_t)NB * 197 * ND;         // 9,682,944
    float* tokA  = ws;
    float* tokB  = tokA + TOKN;
    float* hbuf  = tokB + TOKN;
    float* big   = hbuf + TOKN;                        // 64*197*3072
    float* sm    = big + (size_t)NB * 197 * 3072;
    float* Wt_pe = sm;                                 // 589824
    float* clsA  = Wt_pe + 589824;
    float* clsB  = clsA + 12544;
    float* clsacc = clsB + 12544;
    int*   idxb  = (int*)(clsacc + 12544);
    float* actb  = (float*)(idxb + 12544);
    float* Wt_ad = actb + 1280;                        // 98304

    dim3 blk(16, 16);

    // ---- patch embed
    im2col_kernel<<<(12544 * 768 + 255) / 256, 256, 0, stream>>>(x, hbuf);
    transpose_k<<<(768 * 768 + 255) / 256, 256, 0, stream>>>(patch_w, Wt_pe, 768, 768);
    gemm_f32<0, false><<<dim3(12, 196), blk, 0, stream>>>(hbuf, Wt_pe, patch_b, big, 12544, 768, 768);
    build_tok<<<NB * 197, 256, 0, stream>>>(big, cls_tok, pos, tokA);
    init_cls<<<NB, 256, 0, stream>>>(clsA, clsacc);

    float* tok = tokA; float* tok_alt = tokB;
    float* cls = clsA; float* cls_alt = clsB;
    int curN = 197;

    for (int i = 0; i < NL; ++i) {
        int M = NB * curN;
        ln_kernel<<<M, 256, 0, stream>>>(tok, ln1_g + i * ND, ln1_b + i * ND, hbuf);
        gemm_f32<0, false><<<dim3(36, M / 64), blk, 0, stream>>>(
            hbuf, Wqkv + (size_t)i * ND * 2304, bqkv + (size_t)i * 2304, big, M, 2304, ND);
        attn_kernel<<<NB * NH, 256, 0, stream>>>(big, hbuf, clsacc, curN);
        cls_update<<<NB, 256, 0, stream>>>(cls, clsacc, curN - 1);
        gemm_f32<0, true><<<dim3(12, M / 64), blk, 0, stream>>>(
            hbuf, Wo + (size_t)i * ND * ND, bo + (size_t)i * ND, tok, M, ND, ND);
        ln_kernel<<<M, 256, 0, stream>>>(tok, ln2_g + i * ND, ln2_b + i * ND, hbuf);
        gemm_f32<1, false><<<dim3(48, M / 64), blk, 0, stream>>>(
            hbuf, W1 + (size_t)i * ND * 3072, b1 + (size_t)i * 3072, big, M, 3072, ND);
        gemm_f32<0, true><<<dim3(12, M / 64), blk, 0, stream>>>(
            big, W2 + (size_t)i * 3072 * ND, b2 + (size_t)i * ND, tok, M, ND, 3072);

        if (i == 8 || i == 10) {
            int kk = (i == 8) ? 144 : 121;
            prune_kernel<<<NB, 256, 0, stream>>>(cls, idxb, curN - 1, kk);
            gather_kernel<<<NB * (kk + 1), 256, 0, stream>>>(tok, tok_alt, cls, cls_alt, idxb, kk + 1, curN);
            float* tmp = tok; tok = tok_alt; tok_alt = tmp;
            tmp = cls; cls = cls_alt; cls_alt = tmp;
            curN = kk + 1;
        }
    }

    // ---- head (final top-k of 121/121 is identity; tok rows 1..121 are img)
    copy_img<<<NB * 121, 256, 0, stream>>>(tok, hbuf);
    transpose_k<<<(128 * 768 + 255) / 256, 256, 0, stream>>>(addon_w, Wt_ad, 128, 768);
    gemm_f32<2, false><<<dim3(2, 121), blk, 0, stream>>>(hbuf, Wt_ad, addon_b, big, 7744, 128, 768);
    proto_kernel<<<NB * 20, 128, 0, stream>>>(big, protos, actb);
    final_kernel<<<1, 128, 0, stream>>>(actb, last_w, (float*)d_out);
}

// Round 3
// 29992.023 us; speedup vs baseline: 2.5901x; 2.5901x over previous
//
#include <hip/hip_runtime.h>
#include <hip/hip_bf16.h>
#include <math.h>

// ---------------------------------------------------------------------------
// PPNet (ViT-B/16 + token pruning + proto head). Round 3: bf16 MFMA GEMMs,
// LDS-staged f32 attention. B=64, D=768, H=12, DH=64, L=12, tokens 197->145->122.
// Residual stream (tok) stays f32; GEMM operands bf16; attention math f32.
// ---------------------------------------------------------------------------

#define NB 64
#define ND 768
#define NH 12
#define NL 12
#define NPATCH 196

typedef short     bf16x8 __attribute__((ext_vector_type(8)));
typedef float     f32x4  __attribute__((ext_vector_type(4)));
typedef unsigned short ushort_t;

__device__ __forceinline__ ushort_t f2b(float f) {
    __hip_bfloat16 h = __float2bfloat16(f);
    return *reinterpret_cast<ushort_t*>(&h);
}
__device__ __forceinline__ float gelu_tanh(float x) {
    float x3 = x * x * x;
    return 0.5f * x * (1.0f + tanhf(0.7978845608028654f * (x + 0.044715f * x3)));
}

// ---------------- bf16 MFMA GEMM: C = act(A[Mp,K] @ Bw^T + bias)
// A: bf16 [Mp][K] row-major. Bw: bf16 [N][K] row-major (pre-transposed weight).
// OMODE: 0 = f32 store, 1 = f32 accumulate, 2 = bf16 store. ACT: 0 none, 1 gelu, 2 sigmoid.
// Mp%128==0, N%128==0, K%64==0. Pad rows may hold garbage (finite) - never read back.
template <int ACT, int OMODE>
__global__ __launch_bounds__(256) void gemm_bf16(
    const ushort_t* __restrict__ A, const ushort_t* __restrict__ Bw,
    const float* __restrict__ bias, void* __restrict__ Cv,
    int Mp, int N, int K)
{
    __shared__ ushort_t As[128][64];
    __shared__ ushort_t Bs[128][64];
    const int tid  = threadIdx.x;
    const int wid  = tid >> 6;
    const int lane = tid & 63;
    const int wr   = wid & 1;          // wave row (2x2 wave grid, each 64x64)
    const int wc   = wid >> 1;         // wave col
    const int m0   = blockIdx.y * 128;
    const int n0   = blockIdx.x * 128;

    f32x4 acc[4][4];
#pragma unroll
    for (int i = 0; i < 4; ++i)
#pragma unroll
        for (int j = 0; j < 4; ++j) acc[i][j] = (f32x4){0.f, 0.f, 0.f, 0.f};

    const int rl = lane & 15;
    const int rg = lane >> 4;

    for (int k0 = 0; k0 < K; k0 += 64) {
        bf16x8 va[4], vb[4];
#pragma unroll
        for (int i = 0; i < 4; ++i) {
            int c = tid + 256 * i;
            int row = c >> 3;          // 8 chunks of 16B per 64-elem row
            int kc  = c & 7;
            va[i] = *reinterpret_cast<const bf16x8*>(A  + (size_t)(m0 + row) * K + k0 + kc * 8);
            vb[i] = *reinterpret_cast<const bf16x8*>(Bw + (size_t)(n0 + row) * K + k0 + kc * 8);
        }
        __syncthreads();
#pragma unroll
        for (int i = 0; i < 4; ++i) {
            int c = tid + 256 * i;
            int row = c >> 3;
            int kc  = c & 7;
            *reinterpret_cast<bf16x8*>(&As[row][kc * 8]) = va[i];
            *reinterpret_cast<bf16x8*>(&Bs[row][kc * 8]) = vb[i];
        }
        __syncthreads();
#pragma unroll
        for (int kk = 0; kk < 2; ++kk) {
            const int kb = kk * 32 + rg * 8;
            bf16x8 af[4], bfr[4];
#pragma unroll
            for (int i = 0; i < 4; ++i)
                af[i] = *reinterpret_cast<bf16x8*>(&As[wr * 64 + i * 16 + rl][kb]);
#pragma unroll
            for (int j = 0; j < 4; ++j)
                bfr[j] = *reinterpret_cast<bf16x8*>(&Bs[wc * 64 + j * 16 + rl][kb]);
#pragma unroll
            for (int i = 0; i < 4; ++i)
#pragma unroll
                for (int j = 0; j < 4; ++j)
                    acc[i][j] = __builtin_amdgcn_mfma_f32_16x16x32_bf16(af[i], bfr[j], acc[i][j], 0, 0, 0);
        }
        __syncthreads();
    }

#pragma unroll
    for (int i = 0; i < 4; ++i) {
#pragma unroll
        for (int j = 0; j < 4; ++j) {
            const int col = n0 + wc * 64 + j * 16 + rl;
            const float bv = bias[col];
#pragma unroll
            for (int r = 0; r < 4; ++r) {
                const int row = m0 + wr * 64 + i * 16 + rg * 4 + r;
                float v = acc[i][j][r] + bv;
                if (ACT == 1) v = gelu_tanh(v);
                if (ACT == 2) v = 1.0f / (1.0f + expf(-v));
                const size_t off = (size_t)row * N + col;
                if (OMODE == 0) ((float*)Cv)[off] = v;
                if (OMODE == 1) ((float*)Cv)[off] += v;
                if (OMODE == 2) ((ushort_t*)Cv)[off] = f2b(v);
            }
        }
    }
}

// ---------------- transpose-cast: W f32 [R][C] -> out bf16 [C][R]  (R,C %32==0)
__global__ __launch_bounds__(256) void tcast(const float* __restrict__ W,
                                             ushort_t* __restrict__ out, int R, int C)
{
    __shared__ float t[32][33];
    const int tx = threadIdx.x, ty = threadIdx.y;  // 32 x 8
    const int r0 = blockIdx.y * 32, c0 = blockIdx.x * 32;
#pragma unroll
    for (int k = 0; k < 4; ++k)
        t[ty + 8 * k][tx] = W[(size_t)(r0 + ty + 8 * k) * C + c0 + tx];
    __syncthreads();
#pragma unroll
    for (int k = 0; k < 4; ++k)
        out[(size_t)(c0 + ty + 8 * k) * R + r0 + tx] = f2b(t[tx][ty + 8 * k]);
}

// ---------------- elementwise cast f32 -> bf16
__global__ __launch_bounds__(256) void castw(const float* __restrict__ in,
                                             ushort_t* __restrict__ out, int n)
{
    int i = blockIdx.x * 256 + threadIdx.x;
    if (i < n) out[i] = f2b(in[i]);
}

// ---------------- im2col (bf16 out) for 16x16/stride-16 patch conv
__global__ __launch_bounds__(256) void im2col_bf16(const float* __restrict__ x,
                                                   ushort_t* __restrict__ out)
{
    size_t idx = (size_t)blockIdx.x * 256 + threadIdx.x;
    if (idx >= (size_t)12544 * 768) return;
    int col = (int)(idx % 768);
    int row = (int)(idx / 768);
    int b = row / NPATCH;
    int p = row % NPATCH;
    int c = col >> 8;
    int r = (col & 255) >> 4;
    int j = col & 15;
    int ph = p / 14, pw = p % 14;
    out[idx] = f2b(x[((size_t)(b * 3 + c) * 224 + (ph * 16 + r)) * 224 + (pw * 16 + j)]);
}

// ---------------- build tok = [cls ; patches] + pos (f32)
__global__ __launch_bounds__(256) void build_tok(const float* __restrict__ pe,
                                                 const float* __restrict__ cls_tok,
                                                 const float* __restrict__ pos,
                                                 float* __restrict__ tok)
{
    int bid = blockIdx.x;
    int b = bid / 197, r = bid % 197;
    int t = threadIdx.x;
    float* dst = tok + (size_t)bid * ND;
#pragma unroll
    for (int s = 0; s < 3; ++s) {
        int d = t + s * 256;
        float v = (r == 0) ? cls_tok[d] : pe[(size_t)(b * NPATCH + r - 1) * ND + d];
        dst[d] = v + pos[(size_t)r * ND + d];
    }
}

__global__ __launch_bounds__(256) void init_cls(float* __restrict__ cls)
{
    int b = blockIdx.x, t = threadIdx.x;
    if (t < NPATCH) cls[b * NPATCH + t] = 1.0f;
}

// ---------------- LayerNorm f32 in -> bf16 out (row = 768)
__global__ __launch_bounds__(256) void ln_bf16(const float* __restrict__ x,
                                               const float* __restrict__ g,
                                               const float* __restrict__ b,
                                               ushort_t* __restrict__ out)
{
    __shared__ float red[256];
    int row = blockIdx.x, t = threadIdx.x;
    const float* xr = x + (size_t)row * ND;
    float v0 = xr[t], v1 = xr[t + 256], v2 = xr[t + 512];
    red[t] = v0 + v1 + v2;
    __syncthreads();
    for (int w = 128; w >= 1; w >>= 1) { if (t < w) red[t] += red[t + w]; __syncthreads(); }
    float mean = red[0] * (1.0f / 768.0f);
    __syncthreads();
    float d0 = v0 - mean, d1 = v1 - mean, d2 = v2 - mean;
    red[t] = d0 * d0 + d1 * d1 + d2 * d2;
    __syncthreads();
    for (int w = 128; w >= 1; w >>= 1) { if (t < w) red[t] += red[t + w]; __syncthreads(); }
    float rstd = rsqrtf(red[0] * (1.0f / 768.0f) + 1e-6f);
    ushort_t* o = out + (size_t)row * ND;
    o[t]       = f2b(d0 * rstd * g[t]       + b[t]);
    o[t + 256] = f2b(d1 * rstd * g[t + 256] + b[t + 256]);
    o[t + 512] = f2b(d2 * rstd * g[t + 512] + b[t + 512]);
}

// ---------------- attention (f32 math): one block per (b,h), K/V staged in LDS.
// qkv f32 [rows=b*N+t][2304] = [q|k|v] head-major. o: bf16 [rows][768].
// clsh[b][h][t] = softmax prob of (q=0, key t+1), written for t < N-1.
__global__ __launch_bounds__(256) void attn2(const float* __restrict__ qkv,
                                             ushort_t* __restrict__ o,
                                             float* __restrict__ clsh, int N)
{
    __shared__ float Kt[64][201];     // transposed K, padded (conflict-free)
    __shared__ float Vs[197][64];
    __shared__ float qv[64];
    __shared__ float sc[256];
    __shared__ float redm[4], reds[4];
    __shared__ float pacc[4][64];
    const int bh = blockIdx.x;
    const int b = bh / NH, h = bh % NH;
    const int tid = threadIdx.x, lane = tid & 63, wid = tid >> 6;
    const float* base = qkv + (size_t)b * N * 2304;

    for (int r = wid; r < N; r += 4) {
        Kt[lane][r] = base[(size_t)r * 2304 + 768  + h * 64 + lane];
        Vs[r][lane] = base[(size_t)r * 2304 + 1536 + h * 64 + lane];
    }
    __syncthreads();

    for (int q = 0; q < N; ++q) {
        if (tid < 64) qv[tid] = base[(size_t)q * 2304 + h * 64 + tid];
        __syncthreads();
        float s = -1e30f;
        if (tid < N) {
            float a = 0.f;
#pragma unroll
            for (int d = 0; d < 64; ++d) a += qv[d] * Kt[d][tid];
            s = a * 0.125f;
        }
        float wm = s;
        for (int m = 1; m < 64; m <<= 1) wm = fmaxf(wm, __shfl_xor(wm, m));
        if (lane == 0) redm[wid] = wm;
        __syncthreads();
        float mx = fmaxf(fmaxf(redm[0], redm[1]), fmaxf(redm[2], redm[3]));
        float p = (tid < N) ? expf(s - mx) : 0.f;
        sc[tid] = p;
        float wsum = p;
        for (int m = 1; m < 64; m <<= 1) wsum += __shfl_xor(wsum, m);
        if (lane == 0) reds[wid] = wsum;
        __syncthreads();
        float inv = 1.0f / (reds[0] + reds[1] + reds[2] + reds[3]);
        if (q == 0 && tid >= 1 && tid < N)
            clsh[(size_t)(b * NH + h) * NPATCH + tid - 1] = p * inv;
        float a = 0.f;
        for (int k = wid; k < N; k += 4) a += sc[k] * Vs[k][lane];
        pacc[wid][lane] = a;
        __syncthreads();
        if (tid < 64) {
            float sum = (pacc[0][tid] + pacc[1][tid] + pacc[2][tid] + pacc[3][tid]) * inv;
            o[((size_t)(b * N + q)) * ND + h * 64 + tid] = f2b(sum);
        }
        __syncthreads();
    }
}

// ---------------- cls update: cls *= mean_h clsh; cls /= sum (deterministic)
__global__ __launch_bounds__(256) void cls_update2(float* __restrict__ cls,
                                                   const float* __restrict__ clsh, int n)
{
    __shared__ float red[4];
    const int b = blockIdx.x, t = threadIdx.x, lane = t & 63, wid = t >> 6;
    float v = 0.f;
    if (t < n) {
        float s = 0.f;
#pragma unroll
        for (int h = 0; h < NH; ++h) s += clsh[(size_t)(b * NH + h) * NPATCH + t];
        v = cls[b * NPATCH + t] * (s * (1.0f / 12.0f));
    }
    float w = v;
    for (int m = 1; m < 64; m <<= 1) w += __shfl_xor(w, m);
    if (lane == 0) red[wid] = w;
    __syncthreads();
    float tot = red[0] + red[1] + red[2] + red[3];
    if (t < n) cls[b * NPATCH + t] = v / tot;
}

// ---------------- stable top-k (matches jax.lax.top_k + sorted indices)
__global__ __launch_bounds__(256) void prune_kernel(const float* __restrict__ cls,
                                                    int* __restrict__ idx, int n, int kk)
{
    __shared__ float v[256];
    __shared__ int keep[256];
    int b = blockIdx.x, t = threadIdx.x;
    v[t] = (t < n) ? cls[b * NPATCH + t] : -1e30f;
    __syncthreads();
    if (t < n) {
        float mv = v[t];
        int cnt = 0;
        for (int s = 0; s < n; ++s)
            cnt += (v[s] > mv) || (v[s] == mv && s < t);
        keep[t] = (cnt < kk) ? 1 : 0;
    }
    __syncthreads();
    if (t == 0) {
        int p = 0;
        for (int s = 0; s < n; ++s)
            if (keep[s]) idx[b * NPATCH + p++] = s;
    }
}

// ---------------- gather rows after prune (f32 tok + cls)
__global__ __launch_bounds__(256) void gather_kernel(const float* __restrict__ ti,
                                                     float* __restrict__ to,
                                                     const float* __restrict__ ci,
                                                     float* __restrict__ co,
                                                     const int* __restrict__ idx,
                                                     int newN, int oldN)
{
    int bid = blockIdx.x;
    int b = bid / newN, r = bid % newN;
    int t = threadIdx.x;
    int src = 0;
    if (r > 0) {
        int j = idx[b * NPATCH + r - 1];
        src = 1 + j;
        if (t == 0) co[b * NPATCH + r - 1] = ci[b * NPATCH + j];
    }
    const float* s = ti + (size_t)(b * oldN + src) * ND;
    float* d = to + (size_t)(b * newN + r) * ND;
    d[t] = s[t]; d[t + 256] = s[t + 256]; d[t + 512] = s[t + 512];
}

// ---------------- copy img rows (tok rows 1..121) -> bf16 contiguous
__global__ __launch_bounds__(256) void copy_img_bf16(const float* __restrict__ tok,
                                                     ushort_t* __restrict__ out)
{
    int bid = blockIdx.x;
    int b = bid / 121, r = bid % 121;
    int t = threadIdx.x;
    const float* s = tok + (size_t)(b * 122 + 1 + r) * ND;
    ushort_t* d = out + (size_t)bid * ND;
    d[t] = f2b(s[t]); d[t + 256] = f2b(s[t + 256]); d[t + 512] = f2b(s[t + 512]);
}

// ---------------- proto distances + log activation + max over positions
__global__ __launch_bounds__(128) void proto_kernel(const float* __restrict__ f,
                                                    const float* __restrict__ protos,
                                                    float* __restrict__ act)
{
    __shared__ float pw[128];
    __shared__ float red[128];
    int bid = blockIdx.x;
    int b = bid / 20, p = bid % 20;
    int t = threadIdx.x;
    pw[t] = protos[p * 128 + t];
    __syncthreads();
    float a = -1e30f;
    if (t < 121) {
        const float* fr = f + (size_t)(b * 121 + t) * 128;
        float x2 = 0.f, xp = 0.f, p2 = 0.f;
#pragma unroll
        for (int c = 0; c < 128; ++c) {
            float fv = fr[c], pv = pw[c];
            x2 += fv * fv; xp += fv * pv; p2 += pv * pv;
        }
        float dist = fmaxf(x2 - 2.0f * xp + p2, 0.f);
        a = logf((dist + 1.0f) / (dist + 1e-4f));
    }
    red[t] = a;
    __syncthreads();
    for (int w = 64; w >= 1; w >>= 1) { if (t < w) red[t] = fmaxf(red[t], red[t + w]); __syncthreads(); }
    if (t == 0) act[b * 20 + p] = red[0];
}

__global__ __launch_bounds__(128) void final_kernel(const float* __restrict__ act,
                                                    const float* __restrict__ lw,
                                                    float* __restrict__ out)
{
    int i = threadIdx.x;
    if (i < 128) {
        int b = i >> 1, j = i & 1;
        float s = 0.f;
#pragma unroll
        for (int p = 0; p < 20; ++p) s += act[b * 20 + p] * lw[j * 20 + p];
        out[i] = s;
    }
}

// ---------------------------------------------------------------------------
extern "C" void kernel_launch(void* const* d_in, const int* in_sizes, int n_in,
                              void* d_out, int out_size, void* d_ws, size_t ws_size,
                              hipStream_t stream)
{
    const float* x       = (const float*)d_in[0];
    const float* patch_w = (const float*)d_in[1];
    const float* patch_b = (const float*)d_in[2];
    const float* cls_tok = (const float*)d_in[3];
    const float* pos     = (const float*)d_in[4];
    const float* ln1_g   = (const float*)d_in[5];
    const float* ln1_b   = (const float*)d_in[6];
    const float* Wqkv    = (const float*)d_in[7];
    const float* bqkv    = (const float*)d_in[8];
    const float* Wo      = (const float*)d_in[9];
    const float* bo      = (const float*)d_in[10];
    const float* ln2_g   = (const float*)d_in[11];
    const float* ln2_b   = (const float*)d_in[12];
    const float* W1      = (const float*)d_in[13];
    const float* b1      = (const float*)d_in[14];
    const float* W2      = (const float*)d_in[15];
    const float* b2      = (const float*)d_in[16];
    const float* addon_w = (const float*)d_in[17];
    const float* addon_b = (const float*)d_in[18];
    const float* protos  = (const float*)d_in[19];
    const float* last_w  = (const float*)d_in[20];

    // ---- workspace layout (bytes, 256-aligned)
    char* p = (char*)d_ws;
    auto alloc = [&](size_t bytes) { char* r = p; p += (bytes + 255) & ~size_t(255); return r; };
    const int MPMAX = 12672;                       // ceil(64*197/128)*128
    float*    tokA  = (float*)alloc((size_t)MPMAX * ND * 4);
    float*    tokB  = (float*)alloc((size_t)MPMAX * ND * 4);
    float*    qkvb  = (float*)alloc((size_t)MPMAX * 2304 * 4);   // qkv / patch-out / addon-out
    ushort_t* fc1b  = (ushort_t*)alloc((size_t)MPMAX * 3072 * 2);
    ushort_t* hbuf  = (ushort_t*)alloc((size_t)MPMAX * ND * 2);  // LN out / attn out / img
    ushort_t* wq    = (ushort_t*)alloc((size_t)2304 * 768 * 2);
    ushort_t* wo    = (ushort_t*)alloc((size_t)768 * 768 * 2);
    ushort_t* w1    = (ushort_t*)alloc((size_t)3072 * 768 * 2);
    ushort_t* w2    = (ushort_t*)alloc((size_t)768 * 3072 * 2);
    float*    clsh  = (float*)alloc((size_t)NB * NH * NPATCH * 4);
    float*    clsA  = (float*)alloc((size_t)NB * NPATCH * 4);
    float*    clsB  = (float*)alloc((size_t)NB * NPATCH * 4);
    int*      idxb  = (int*)alloc((size_t)NB * NPATCH * 4);
    float*    actb  = (float*)alloc(1280 * 4);
    ushort_t* imcol = fc1b;            // reuse: patch stage finishes before fc1 use
    ushort_t* wpe   = w1;              // reuse: patch GEMM before layer-0 tcasts
    ushort_t* wad   = wq;              // reuse: head runs after last layer GEMMs

    dim3 blk8(32, 8);

    // ---- patch embed (bf16 GEMM: A=im2col, B=patch_w [N][K] cast-only)
    im2col_bf16<<<(12544 * 768 + 255) / 256, 256, 0, stream>>>(x, imcol);
    castw<<<(768 * 768 + 255) / 256, 256, 0, stream>>>(patch_w, wpe, 768 * 768);
    gemm_bf16<0, 0><<<dim3(6, 98), 256, 0, stream>>>(imcol, wpe, patch_b, qkvb, 12544, 768, 768);
    build_tok<<<NB * 197, 256, 0, stream>>>(qkvb, cls_tok, pos, tokA);
    init_cls<<<NB, 256, 0, stream>>>(clsA);

    float* tok = tokA; float* tok_alt = tokB;
    float* cls = clsA; float* cls_alt = clsB;
    int curN = 197;

    for (int i = 0; i < NL; ++i) {
        const int M  = NB * curN;
        const int Mp = (M + 127) / 128 * 128;
        // per-layer weight transpose-casts ([K][N] f32 -> [N][K] bf16)
        tcast<<<dim3(2304 / 32, 768 / 32),  blk8, 0, stream>>>(Wqkv + (size_t)i * 768 * 2304, wq, 768, 2304);
        tcast<<<dim3(768 / 32,  768 / 32),  blk8, 0, stream>>>(Wo   + (size_t)i * 768 * 768,  wo, 768, 768);
        tcast<<<dim3(3072 / 32, 768 / 32),  blk8, 0, stream>>>(W1   + (size_t)i * 768 * 3072, w1, 768, 3072);
        tcast<<<dim3(768 / 32,  3072 / 32), blk8, 0, stream>>>(W2   + (size_t)i * 3072 * 768, w2, 3072, 768);

        ln_bf16<<<M, 256, 0, stream>>>(tok, ln1_g + i * ND, ln1_b + i * ND, hbuf);
        gemm_bf16<0, 0><<<dim3(18, Mp / 128), 256, 0, stream>>>(hbuf, wq, bqkv + (size_t)i * 2304, qkvb, Mp, 2304, 768);
        attn2<<<NB * NH, 256, 0, stream>>>(qkvb, hbuf, clsh, curN);
        cls_update2<<<NB, 256, 0, stream>>>(cls, clsh, curN - 1);
        gemm_bf16<0, 1><<<dim3(6, Mp / 128), 256, 0, stream>>>(hbuf, wo, bo + (size_t)i * ND, tok, Mp, 768, 768);
        ln_bf16<<<M, 256, 0, stream>>>(tok, ln2_g + i * ND, ln2_b + i * ND, hbuf);
        gemm_bf16<1, 2><<<dim3(24, Mp / 128), 256, 0, stream>>>(hbuf, w1, b1 + (size_t)i * 3072, fc1b, Mp, 3072, 768);
        gemm_bf16<0, 1><<<dim3(6, Mp / 128), 256, 0, stream>>>(fc1b, w2, b2 + (size_t)i * ND, tok, Mp, 768, 3072);

        if (i == 8 || i == 10) {
            int kk = (i == 8) ? 144 : 121;
            prune_kernel<<<NB, 256, 0, stream>>>(cls, idxb, curN - 1, kk);
            gather_kernel<<<NB * (kk + 1), 256, 0, stream>>>(tok, tok_alt, cls, cls_alt, idxb, kk + 1, curN);
            float* tmp = tok; tok = tok_alt; tok_alt = tmp;
            tmp = cls; cls = cls_alt; cls_alt = tmp;
            curN = kk + 1;
        }
    }

    // ---- head: img rows -> addon GEMM (sigmoid) -> proto -> final
    copy_img_bf16<<<NB * 121, 256, 0, stream>>>(tok, hbuf);
    castw<<<(128 * 768 + 255) / 256, 256, 0, stream>>>(addon_w, wad, 128 * 768);
    gemm_bf16<2, 0><<<dim3(1, 7808 / 128), 256, 0, stream>>>(hbuf, wad, addon_b, qkvb, 7808, 128, 768);
    proto_kernel<<<NB * 20, 128, 0, stream>>>(qkvb, protos, actb);
    final_kernel<<<1, 128, 0, stream>>>(actb, last_w, (float*)d_out);
}